// Round 12
// baseline (256.835 us; speedup 1.0000x reference)
//
#include <hip/hip_runtime.h>

// ---------------- problem constants ----------------
#define NBATCH 4
#define SEQ    4096
#define DMODEL 512
#define NHEAD  8
#define HDIM   64
#define NSN    32
#define NXT    2048
#define QLEN   2080   // NXT + NSN
#define KLEN   4128   // SEQ + NSN

using bf16x8 = __attribute__((ext_vector_type(8))) short;
using f32x4  = __attribute__((ext_vector_type(4))) float;

typedef __attribute__((address_space(1))) unsigned int gu32;
typedef __attribute__((address_space(3))) unsigned int lu32;

// Q projection pre-scale: SCALE * log2(e) — softmax runs in exp2 domain
#define QSCALE 0.18033688f

__device__ __forceinline__ unsigned short f2bf(float f) {
  unsigned int u = __float_as_uint(f);
  u += 0x7FFF + ((u >> 16) & 1);          // RTNE
  return (unsigned short)(u >> 16);
}

__device__ __forceinline__ float bf2f(unsigned short u) {
  return __uint_as_float((unsigned int)u << 16);
}

__device__ __forceinline__ f32x4 mfma16(bf16x8 a, bf16x8 b, f32x4 c) {
  return __builtin_amdgcn_mfma_f32_16x16x32_bf16(a, b, c, 0, 0, 0);
}

__device__ __forceinline__ void gload_lds16(const void* g, void* lds_base) {
  __builtin_amdgcn_global_load_lds((const gu32*)g, (lu32*)lds_base, 16, 0, 0);
}

__device__ __forceinline__ unsigned int cvt_pk_bf16(float lo, float hi) {
  unsigned int r;
  asm("v_cvt_pk_bf16_f32 %0, %1, %2" : "=v"(r) : "v"(lo), "v"(hi));
  return r;
}

// ---------------- fp32 -> bf16 converts ----------------
__global__ __launch_bounds__(256) void cvt_f32_bf16_v4(const float* __restrict__ src,
                                                       unsigned short* __restrict__ dst, int n4) {
  int i = blockIdx.x * 256 + threadIdx.x;
  if (i >= n4) return;
  float4 v = reinterpret_cast<const float4*>(src)[i];
  ushort4 r;
  r.x = f2bf(v.x); r.y = f2bf(v.y); r.z = f2bf(v.z); r.w = f2bf(v.w);
  reinterpret_cast<ushort4*>(dst)[i] = r;
}

__global__ __launch_bounds__(256) void cvt_w4(const float* __restrict__ a, const float* __restrict__ b,
                                              const float* __restrict__ c, const float* __restrict__ d,
                                              unsigned short* __restrict__ dst) {
  const float* s = blockIdx.y == 0 ? a : blockIdx.y == 1 ? b : blockIdx.y == 2 ? c : d;
  int i = blockIdx.x * 256 + threadIdx.x;   // 65536 float4 per matrix
  float4 v = reinterpret_cast<const float4*>(s)[i];
  ushort4 r;
  r.x = f2bf(v.x); r.y = f2bf(v.y); r.z = f2bf(v.z); r.w = f2bf(v.w);
  reinterpret_cast<ushort4*>(dst)[(size_t)blockIdx.y * 65536 + i] = r;
}

// ---------------- seq projection GEMM (m97 structure, known-good) ----------------
__global__ __launch_bounds__(256) void proj_gemm(const unsigned short* __restrict__ X,
                                                 const unsigned short* __restrict__ W,
                                                 unsigned short* __restrict__ Out,
                                                 int rpb_shift, int row_off, int out_L, float scale) {
  __shared__ unsigned short As[128 * 32];
  __shared__ unsigned short Bs[128 * 32];
  const int tid = threadIdx.x;
  const int w = tid >> 6, l = tid & 63;
  const int lg = l >> 4, lr = l & 15;
  const int row0 = blockIdx.x * 128, col0 = blockIdx.y * 128;
  const int wr = (w >> 1) * 64, wc = (w & 1) * 64;
  const int mask = (1 << rpb_shift) - 1;

  f32x4 acc[4][4];
#pragma unroll
  for (int m = 0; m < 4; ++m)
#pragma unroll
    for (int n = 0; n < 4; ++n) acc[m][n] = (f32x4){0.f, 0.f, 0.f, 0.f};

  const int sr = w * 16 + (l >> 2);
  const int sc = (l & 3) * 8;

  for (int k0 = 0; k0 < 512; k0 += 32) {
#pragma unroll
    for (int i = 0; i < 2; ++i) {
      int gr = row0 + sr + i * 64;
      int xrow = ((gr >> rpb_shift) << 12) + row_off + (gr & mask);
      const unsigned short* gpa = X + (size_t)xrow * 512 + k0 + sc;
      gload_lds16(gpa, (char*)As + i * 4096 + w * 1024);
      const unsigned short* gpb = W + (size_t)(col0 + sr + i * 64) * 512 + k0 + sc;
      gload_lds16(gpb, (char*)Bs + i * 4096 + w * 1024);
    }
    __syncthreads();
    bf16x8 av[4], bv[4];
#pragma unroll
    for (int m = 0; m < 4; ++m) av[m] = *(const bf16x8*)&As[(wr + m * 16 + lr) * 32 + lg * 8];
#pragma unroll
    for (int n = 0; n < 4; ++n) bv[n] = *(const bf16x8*)&Bs[(wc + n * 16 + lr) * 32 + lg * 8];
#pragma unroll
    for (int m = 0; m < 4; ++m)
#pragma unroll
      for (int n = 0; n < 4; ++n) acc[m][n] = mfma16(av[m], bv[n], acc[m][n]);
    __syncthreads();
  }

#pragma unroll
  for (int m = 0; m < 4; ++m) {
    int crow = row0 + wr + m * 16 + lg * 4;
#pragma unroll
    for (int n = 0; n < 4; ++n) {
      int ccol = col0 + wc + n * 16 + lr;
      int hh = ccol >> 6, dd = ccol & 63;
#pragma unroll
      for (int r = 0; r < 4; ++r) {
        int cr = crow + r;
        int bb = cr >> rpb_shift, ii = cr & mask;
        Out[(((size_t)bb * NHEAD + hh) * out_L + ii) * HDIM + dd] = f2bf(acc[m][n][r] * scale);
      }
    }
  }
}

// ---------------- ns projections ----------------
__global__ __launch_bounds__(256) void ns_proj(const float* __restrict__ nst,
                                               const float* __restrict__ Wnq, const float* __restrict__ Wnk,
                                               const float* __restrict__ Wnv,
                                               unsigned short* __restrict__ Qb, unsigned short* __restrict__ Kb,
                                               unsigned short* __restrict__ Vb) {
  const int oc = blockIdx.x, n = blockIdx.y, p = blockIdx.z;
  const float* W = p == 0 ? Wnq : p == 1 ? Wnk : Wnv;
  unsigned short* Out = p == 0 ? Qb : p == 1 ? Kb : Vb;
  const int out_L = p == 0 ? QLEN : KLEN;
  const int orow = p == 0 ? NXT + n : SEQ + n;
  const float scale = p == 0 ? QSCALE : 1.f;

  __shared__ float xs[NBATCH][DMODEL];
  __shared__ float red[NBATCH][128];
  const int tid = threadIdx.x;
  for (int idx = tid; idx < NBATCH * DMODEL; idx += 256)
    xs[idx >> 9][idx & 511] = nst[(size_t)((idx >> 9) * NSN + n) * DMODEL + (idx & 511)];
  __syncthreads();

  const int o = oc * 128 + (tid & 127);
  const int dh = tid >> 7;
  float a0 = 0.f, a1 = 0.f, a2 = 0.f, a3 = 0.f;
  const float* wp = W + (size_t)n * DMODEL * DMODEL + o;
#pragma unroll 8
  for (int d = dh * 256; d < dh * 256 + 256; ++d) {
    float wv = wp[(size_t)d * DMODEL];
    a0 += xs[0][d] * wv; a1 += xs[1][d] * wv; a2 += xs[2][d] * wv; a3 += xs[3][d] * wv;
  }
  if (dh == 1) { red[0][tid & 127] = a0; red[1][tid & 127] = a1; red[2][tid & 127] = a2; red[3][tid & 127] = a3; }
  __syncthreads();
  if (dh == 0) {
    a0 += red[0][tid & 127]; a1 += red[1][tid & 127]; a2 += red[2][tid & 127]; a3 += red[3][tid & 127];
    int hh = o >> 6, dd = o & 63;
    float v[4] = {a0, a1, a2, a3};
#pragma unroll
    for (int b = 0; b < NBATCH; ++b)
      Out[(((size_t)b * NHEAD + hh) * out_L + orow) * HDIM + dd] = f2bf(v[b] * scale);
  }
}

// ---------------- global V transpose: Vt[bh][d][kv] = V[bh][kv][d] ----------------
__global__ __launch_bounds__(256) void vtrans(const unsigned short* __restrict__ V,
                                              unsigned short* __restrict__ Vt) {
  __shared__ unsigned short t[64 * 64];
  const int tid = threadIdx.x;
  const int kv0 = blockIdx.x * 64, bh = blockIdx.y;
  const unsigned short* Vhp = V + (size_t)bh * KLEN * HDIM;
  unsigned short* Vtp = Vt + (size_t)bh * HDIM * KLEN;

#pragma unroll
  for (int i = 0; i < 2; ++i) {
    int c = i * 256 + tid;
    int row = c >> 3, c8 = c & 7;
    int kvg = kv0 + row; if (kvg > KLEN - 1) kvg = KLEN - 1;
    int4 v4 = *(const int4*)(Vhp + (size_t)kvg * HDIM + c8 * 8);
    *(int4*)&t[row * 64 + ((c8 ^ ((row >> 3) & 7)) * 8)] = v4;
  }
  __syncthreads();
#pragma unroll
  for (int i = 0; i < 2; ++i) {
    int c = i * 256 + tid;
    int d = c >> 3, k8 = c & 7;
    if (kv0 + k8 * 8 <= KLEN - 8) {
      unsigned int wd[4];
#pragma unroll
      for (int jj = 0; jj < 4; ++jj) {
        int ka = k8 * 8 + jj * 2, kb2 = ka + 1;
        unsigned int lo = t[ka  * 64 + (((d >> 3) ^ ((ka  >> 3) & 7)) * 8) + (d & 7)];
        unsigned int hi = t[kb2 * 64 + (((d >> 3) ^ ((kb2 >> 3) & 7)) * 8) + (d & 7)];
        wd[jj] = lo | (hi << 16);
      }
      int4 o; o.x = wd[0]; o.y = wd[1]; o.z = wd[2]; o.w = wd[3];
      *(int4*)(Vtp + (size_t)d * KLEN + kv0 + k8 * 8) = o;
    }
  }
}

// ---------------- flash attention (R12: 32q/wave, QBLK=128, split-K x3) -----------
// Each wave owns 32 q-rows (2 subtiles qt=0,1). K-fragment reads are shared across
// both subtiles and each V-fragment read feeds both accumulators -> LDS reads per
// unit work HALVE vs R11 (the co-binding resource). Staging uses incrementing
// pointers (clamped path only for kb==64). waves_per_eu(1,4) -> 128-VGPR budget
// (demand ~115; R3/R4 showed the default heuristic picks 64-72 and spills).
// Grid (51,8,4): 17 qb x 3 splits; partial layout identical to R11.
__global__ __launch_bounds__(256)
__attribute__((amdgpu_waves_per_eu(1, 4)))
void attn_kernel(const unsigned short* __restrict__ Qb,
                 const unsigned short* __restrict__ Kb,
                 const unsigned short* __restrict__ Vtg,
                 unsigned short* __restrict__ PoA,
                 float2* __restrict__ PmlA,
                 unsigned short* __restrict__ PoB,
                 float2* __restrict__ PmlB) {
  __shared__ unsigned short Ks[64 * 64];   // 8 KB [kv][d] swizzled
  __shared__ unsigned short Vs[64 * 64];   // 8 KB [d][kv] swizzled

  const int tid = threadIdx.x;
  const int w = tid >> 6, l = tid & 63;
  const int lg = l >> 4, lr = l & 15;
  const bool geven = (l & 16) == 0;
  const int bx = (int)blockIdx.x;
  const int qb = 16 - bx / 3;                          // big q-blocks first
  const int sp = bx - 3 * (16 - qb);
  const int bh = (int)blockIdx.z * NHEAD + (int)blockIdx.y;
  const int q0 = qb * 128;
  const int base = NXT + q0;
  int nkb = (base >> 6) + 2; if (nkb > 65) nkb = 65;   // tiles (incl. 2 diag)
  const int kbm = base >> 6;                           // first masked tile
  const int t0 = (sp * nkb) / 3;
  const int t1 = ((sp + 1) * nkb) / 3;

  const unsigned short* Qh = Qb + (size_t)bh * QLEN * HDIM;
  const unsigned short* Kh = Kb + (size_t)bh * KLEN * HDIM;
  const unsigned short* Vh = Vtg + (size_t)bh * HDIM * KLEN;   // [64][KLEN]

  // Q fragments for both subtiles
  bf16x8 qa[2][2];
#pragma unroll
  for (int qt = 0; qt < 2; ++qt) {
    int qrow = q0 + w * 32 + qt * 16 + lr; if (qrow > QLEN - 1) qrow = QLEN - 1;
    qa[qt][0] = *(const bf16x8*)(Qh + (size_t)qrow * HDIM + lg * 8);
    qa[qt][1] = *(const bf16x8*)(Qh + (size_t)qrow * HDIM + 32 + lg * 8);
  }

  f32x4 acc0[4], acc1[4];
#pragma unroll
  for (int n = 0; n < 4; ++n) {
    acc0[n] = (f32x4){0.f, 0.f, 0.f, 0.f};
    acc1[n] = (f32x4){0.f, 0.f, 0.f, 0.f};
  }
  float m_r[2] = {0.f, 0.f}, lsum[2] = {0.f, 0.f};
  f32x4 mini[2] = {(f32x4){0.f, 0.f, 0.f, 0.f}, (f32x4){0.f, 0.f, 0.f, 0.f}};

  const bf16x8 ones = {(short)0x3F80, (short)0x3F80, (short)0x3F80, (short)0x3F80,
                       (short)0x3F80, (short)0x3F80, (short)0x3F80, (short)0x3F80};

  // staging lane geometry (involutive chunk swizzle, rule #21); running pointers
  const int rloc = l >> 3;
  const int jsrc = ((l & 7) ^ rloc) * 8;
  const int r8a = (w * 2) * 8, r8b = (w * 2 + 1) * 8;
  const unsigned short* kpa = Kh + (size_t)(t0 * 64 + r8a + rloc) * HDIM + jsrc;
  const unsigned short* kpb = Kh + (size_t)(t0 * 64 + r8b + rloc) * HDIM + jsrc;
  const unsigned short* vpa = Vh + (size_t)(r8a + rloc) * KLEN + t0 * 64 + jsrc;
  const unsigned short* vpb = Vh + (size_t)(r8b + rloc) * KLEN + t0 * 64 + jsrc;

  for (int kb = t0; kb < t1; ++kb) {
    if (kb != 64) {                                    // fast staging (full tile)
      gload_lds16(kpa, &Ks[r8a * 64]);
      gload_lds16(kpb, &Ks[r8b * 64]);
      gload_lds16(vpa, &Vs[r8a * 64]);
      gload_lds16(vpb, &Vs[r8b * 64]);
      kpa += 64 * HDIM; kpb += 64 * HDIM; vpa += 64; vpb += 64;
    } else {                                           // boundary tile (kv 4096..4159)
#pragma unroll
      for (int i = 0; i < 2; ++i) {
        const int r8 = (w * 2 + i) * 8;
        int kr = 4096 + r8 + rloc; if (kr > KLEN - 1) kr = KLEN - 1;
        gload_lds16(Kh + (size_t)kr * HDIM + jsrc, &Ks[r8 * 64]);
        int vc = 4096 + jsrc; if (vc > KLEN - 8) vc = KLEN - 8;
        gload_lds16(Vh + (size_t)(r8 + rloc) * KLEN + vc, &Vs[r8 * 64]);
      }
    }
    __syncthreads();                                   // DMA drained, tile ready

    const int kv0 = kb * 64;

    // S^T = K Q^T - m for both q-subtiles; K-fragments read ONCE
    f32x4 s0[4], s1[4];
#pragma unroll
    for (int n = 0; n < 4; ++n) {
      const int rk = n * 16 + lr;
      const bf16x8 k0 = *(const bf16x8*)&Ks[rk * 64 + ((lg ^ (rk & 7)) * 8)];
      const bf16x8 k1 = *(const bf16x8*)&Ks[rk * 64 + (((4 + lg) ^ (rk & 7)) * 8)];
      s0[n] = mfma16(k0, qa[0][0], mini[0]);
      s0[n] = mfma16(k1, qa[0][1], s0[n]);
      s1[n] = mfma16(k0, qa[1][0], mini[1]);
      s1[n] = mfma16(k1, qa[1][1], s1[n]);
    }

    if (kb >= kbm) {                                   // causal mask (2 diag tiles)
      const int qp0 = base + w * 32 + lr;
      const int qp1 = qp0 + 16;
#pragma unroll
      for (int n = 0; n < 4; ++n) {
        const int kvb = kv0 + n * 16 + lg * 4;
#pragma unroll
        for (int r = 0; r < 4; ++r) {
          if (kvb + r > qp0) s0[n][r] = -1e30f;
          if (kvb + r > qp1) s1[n][r] = -1e30f;
        }
      }
    }

    // local max over all 32 values (v_max3 triples); __any is wave-global
    float x0 = fmaxf(fmaxf(s0[0][0], s0[0][1]), s0[0][2]);
    float x1 = fmaxf(fmaxf(s0[0][3], s0[1][0]), s0[1][1]);
    float x2 = fmaxf(fmaxf(s0[1][2], s0[1][3]), s0[2][0]);
    float x3 = fmaxf(fmaxf(s0[2][1], s0[2][2]), s0[2][3]);
    float x4 = fmaxf(fmaxf(s0[3][0], s0[3][1]), s0[3][2]);
    float x5 = fmaxf(fmaxf(s0[3][3], s1[0][0]), s1[0][1]);
    float x6 = fmaxf(fmaxf(s1[0][2], s1[0][3]), s1[1][0]);
    float x7 = fmaxf(fmaxf(s1[1][1], s1[1][2]), s1[1][3]);
    float x8 = fmaxf(fmaxf(s1[2][0], s1[2][1]), s1[2][2]);
    float x9 = fmaxf(fmaxf(s1[2][3], s1[3][0]), s1[3][1]);
    float rl = fmaxf(fmaxf(x0, x1), x2);
    rl = fmaxf(fmaxf(rl, x3), x4);
    rl = fmaxf(fmaxf(rl, x5), x6);
    rl = fmaxf(fmaxf(rl, x7), x8);
    rl = fmaxf(fmaxf(rl, x9), fmaxf(s1[3][2], s1[3][3]));

    if (__any(rl > 11.5f)) {                           // T13 defer-max (rare)
      float rm0 = fmaxf(fmaxf(fmaxf(x0, x1), x2), fmaxf(fmaxf(x3, x4), s0[3][3]));
      float rm1 = fmaxf(fmaxf(fmaxf(fmaxf(s1[0][0], s1[0][1]), fmaxf(s1[0][2], s1[0][3])), x7),
                        fmaxf(fmaxf(x8, x9), fmaxf(fmaxf(s1[1][0], s1[3][2]), s1[3][3])));
      rm0 = fmaxf(rm0, __shfl_xor(rm0, 16)); rm0 = fmaxf(rm0, __shfl_xor(rm0, 32));
      rm1 = fmaxf(rm1, __shfl_xor(rm1, 16)); rm1 = fmaxf(rm1, __shfl_xor(rm1, 32));
      float dl0 = fmaxf(rm0, 0.f), dl1 = fmaxf(rm1, 0.f);
      float sc0 = exp2f(-dl0), sc1 = exp2f(-dl1);
      lsum[0] *= sc0; lsum[1] *= sc1;
      m_r[0] += dl0; m_r[1] += dl1;
      mini[0] = (f32x4){-m_r[0], -m_r[0], -m_r[0], -m_r[0]};
      mini[1] = (f32x4){-m_r[1], -m_r[1], -m_r[1], -m_r[1]};
#pragma unroll
      for (int n = 0; n < 4; ++n) {
#pragma unroll
        for (int r = 0; r < 4; ++r) {
          acc0[n][r] *= sc0; acc1[n][r] *= sc1;
          s0[n][r] = exp2f(s0[n][r] - dl0);
          s1[n][r] = exp2f(s1[n][r] - dl1);
        }
      }
    } else {
#pragma unroll
      for (int n = 0; n < 4; ++n)
#pragma unroll
        for (int r = 0; r < 4; ++r) {
          s0[n][r] = exp2f(s0[n][r]);
          s1[n][r] = exp2f(s1[n][r]);
        }
    }

    // ---- P redistribution (registers only) for both subtiles ----
    bf16x8 pb0[2], pb1[2];
#pragma unroll
    for (int qt = 0; qt < 2; ++qt) {
      f32x4* s = qt ? s1 : s0;
      unsigned int wpk[4][2];
#pragma unroll
      for (int n = 0; n < 4; ++n) {
        wpk[n][0] = cvt_pk_bf16(s[n][0], s[n][1]);
        wpk[n][1] = cvt_pk_bf16(s[n][2], s[n][3]);
      }
      bf16x8* pb = qt ? pb1 : pb0;
#pragma unroll
      for (int ks = 0; ks < 2; ++ks) {
        unsigned int A0 = wpk[2 * ks][0], B0 = wpk[2 * ks + 1][0];
        unsigned int A1 = wpk[2 * ks][1], B1 = wpk[2 * ks + 1][1];
        asm("v_permlane32_swap_b32 %0, %1" : "+v"(A0), "+v"(B0));
        asm("v_permlane32_swap_b32 %0, %1" : "+v"(A1), "+v"(B1));
        unsigned int sA0 = __builtin_amdgcn_ds_swizzle(A0, 0x401F);  // lane ^16
        unsigned int sA1 = __builtin_amdgcn_ds_swizzle(A1, 0x401F);
        unsigned int sB0 = __builtin_amdgcn_ds_swizzle(B0, 0x401F);
        unsigned int sB1 = __builtin_amdgcn_ds_swizzle(B1, 0x401F);
        int4 words;
        words.x = geven ? A0 : sB0;
        words.y = geven ? A1 : sB1;
        words.z = geven ? sA0 : B0;
        words.w = geven ? sA1 : B1;
        pb[ks] = *(bf16x8*)&words;    // B-frag: P[kv=32ks+(l>>4)*8+j][q=l&15]
      }
    }

    // lsum via ones-MFMA (A=ones), per subtile
    f32x4 as0 = (f32x4){0.f, 0.f, 0.f, 0.f};
    as0 = mfma16(ones, pb0[0], as0);
    as0 = mfma16(ones, pb0[1], as0);
    lsum[0] += as0[0];
    f32x4 as1 = (f32x4){0.f, 0.f, 0.f, 0.f};
    as1 = mfma16(ones, pb1[0], as1);
    as1 = mfma16(ones, pb1[1], as1);
    lsum[1] += as1[0];

    // PV: V-fragments read ONCE, feed both accumulators
#pragma unroll
    for (int n = 0; n < 4; ++n) {
      const int rv = n * 16 + lr;
#pragma unroll
      for (int ks = 0; ks < 2; ++ks) {
        const bf16x8 vv = *(const bf16x8*)&Vs[rv * 64 + (((ks * 4 + lg) ^ (rv & 7)) * 8)];
        acc0[n] = mfma16(vv, pb0[ks], acc0[n]);
        acc1[n] = mfma16(vv, pb1[ks], acc1[n]);
      }
    }

    __syncthreads();   // readers done before next tile's DMA overwrites
  }

  // store partials (packed 8B) per subtile
#pragma unroll
  for (int qt = 0; qt < 2; ++qt) {
    const int qi = q0 + w * 32 + qt * 16 + lr;
    if (qi < QLEN) {
      f32x4* acc = qt ? acc1 : acc0;
      unsigned short* po; float2* pml; size_t rowp;
      if (sp < 2) { rowp = (size_t)(sp * 32 + bh) * QLEN + qi; po = PoA + rowp * 64; pml = PmlA + rowp; }
      else        { rowp = (size_t)bh * QLEN + qi;             po = PoB + rowp * 64; pml = PmlB + rowp; }
#pragma unroll
      for (int n = 0; n < 4; ++n) {
        ushort4 pk;
        pk.x = f2bf(acc[n][0]); pk.y = f2bf(acc[n][1]);
        pk.z = f2bf(acc[n][2]); pk.w = f2bf(acc[n][3]);
        *(ushort4*)(po + n * 16 + lg * 4) = pk;
      }
      if (l < 16) *pml = (float2){m_r[qt], lsum[qt]};
    }
  }
}

// ---------------- split-K combine (3-way) ----------------
__global__ __launch_bounds__(256) void attn_combine(const unsigned short* __restrict__ PoA,
                                                    const float2* __restrict__ PmlA,
                                                    const unsigned short* __restrict__ PoB,
                                                    const float2* __restrict__ PmlB,
                                                    unsigned short* __restrict__ Att) {
  const int bh = blockIdx.y;
  const int idx = blockIdx.x * 256 + threadIdx.x;
  const int qi = idx >> 3, dc = (idx & 7) * 8;
  const size_t row = (size_t)bh * QLEN + qi;
  const float2 ml0 = PmlA[row];
  const float2 ml1 = PmlA[(size_t)32 * QLEN + row];
  const float2 ml2 = PmlB[row];
  const float mm = fmaxf(fmaxf(ml0.x, ml1.x), ml2.x);
  float s0 = exp2f(ml0.x - mm), s1 = exp2f(ml1.x - mm), s2 = exp2f(ml2.x - mm);
  const float inv = 1.f / (ml0.y * s0 + ml1.y * s1 + ml2.y * s2);
  s0 *= inv; s1 *= inv; s2 *= inv;
  const bf16x8 o0 = *(const bf16x8*)(PoA + row * 64 + dc);
  const bf16x8 o1 = *(const bf16x8*)(PoA + ((size_t)32 * QLEN + row) * 64 + dc);
  const bf16x8 o2 = *(const bf16x8*)(PoB + row * 64 + dc);
  unsigned short out[8];
#pragma unroll
  for (int j = 0; j < 8; ++j)
    out[j] = f2bf(bf2f((unsigned short)o0[j]) * s0 + bf2f((unsigned short)o1[j]) * s1 +
                  bf2f((unsigned short)o2[j]) * s2);
  const int b = bh >> 3, h = bh & 7;
  *(int4*)(Att + ((size_t)b * QLEN + qi) * DMODEL + h * HDIM + dc) = *(int4*)out;
}

// ---------------- output GEMM (unchanged) ----------------
__global__ __launch_bounds__(256) void out_gemm(const unsigned short* __restrict__ A,
                                                const unsigned short* __restrict__ W,
                                                float* __restrict__ Out) {
  __shared__ unsigned short As[128 * 32];
  __shared__ unsigned short Bs[128 * 32];
  const int tid = threadIdx.x;
  const int w = tid >> 6, l = tid & 63;
  const int lg = l >> 4, lr = l & 15;
  const int row0 = blockIdx.x * 128, col0 = blockIdx.y * 128;
  const int wr = (w >> 1) * 64, wc = (w & 1) * 64;

  f32x4 acc[4][4];
#pragma unroll
  for (int m = 0; m < 4; ++m)
#pragma unroll
    for (int n = 0; n < 4; ++n) acc[m][n] = (f32x4){0.f, 0.f, 0.f, 0.f};

  const int sr = w * 16 + (l >> 2);
  const int sc = (l & 3) * 8;

  for (int k0 = 0; k0 < 512; k0 += 32) {
#pragma unroll
    for (int i = 0; i < 2; ++i) {
      const unsigned short* gpa = A + (size_t)(row0 + sr + i * 64) * 512 + k0 + sc;
      gload_lds16(gpa, (char*)As + i * 4096 + w * 1024);
      const unsigned short* gpb = W + (size_t)(col0 + sr + i * 64) * 512 + k0 + sc;
      gload_lds16(gpb, (char*)Bs + i * 4096 + w * 1024);
    }
    __syncthreads();
    bf16x8 av[4], bv[4];
#pragma unroll
    for (int m = 0; m < 4; ++m) av[m] = *(const bf16x8*)&As[(wr + m * 16 + lr) * 32 + lg * 8];
#pragma unroll
    for (int n = 0; n < 4; ++n) bv[n] = *(const bf16x8*)&Bs[(wc + n * 16 + lr) * 32 + lg * 8];
#pragma unroll
    for (int m = 0; m < 4; ++m)
#pragma unroll
      for (int n = 0; n < 4; ++n) acc[m][n] = mfma16(av[m], bv[n], acc[m][n]);
    __syncthreads();
  }

#pragma unroll
  for (int m = 0; m < 4; ++m) {
    int crow = row0 + wr + m * 16 + lg * 4;
#pragma unroll
    for (int n = 0; n < 4; ++n) {
      int ccol = col0 + wc + n * 16 + lr;
#pragma unroll
      for (int r = 0; r < 4; ++r) {
        int cr = crow + r;
        int bb = cr / QLEN, ii = cr - bb * QLEN;
        size_t off = ii < NXT
                       ? ((size_t)bb * NXT + ii) * DMODEL + ccol
                       : (size_t)NBATCH * NXT * DMODEL + ((size_t)bb * NSN + (ii - NXT)) * DMODEL + ccol;
        Out[off] = acc[m][n][r];
      }
    }
  }
}

// ---------------- host launch ----------------
extern "C" void kernel_launch(void* const* d_in, const int* in_sizes, int n_in,
                              void* d_out, int out_size, void* d_ws, size_t ws_size,
                              hipStream_t stream) {
  const float* seq = (const float*)d_in[0];
  const float* nst = (const float*)d_in[2];
  const float* Wq  = (const float*)d_in[5];
  const float* Wk  = (const float*)d_in[6];
  const float* Wv  = (const float*)d_in[7];
  const float* nsq = (const float*)d_in[8];
  const float* nsk = (const float*)d_in[9];
  const float* nsv = (const float*)d_in[10];
  const float* Wo  = (const float*)d_in[11];
  float* out = (float*)d_out;

  char* ws = (char*)d_ws;
  unsigned short* Xbf  = (unsigned short*)(ws);                       // 16,777,216 (dead after Q proj)
  unsigned short* Wqb  = (unsigned short*)(ws + 16777216);            // 524,288 x4 (Wq/k/v dead after projs)
  unsigned short* Wkb  = Wqb + 262144;
  unsigned short* Wvb  = Wkb + 262144;
  unsigned short* Wob  = Wvb + 262144;                                // LIVE until out_gemm
  unsigned short* Qbuf = (unsigned short*)(ws + 18874368);            // 8,519,680
  unsigned short* Kbuf = (unsigned short*)(ws + 27394048);            // 16,908,288
  unsigned short* Vbuf = (unsigned short*)(ws + 44302336);            // 16,908,288 (dead after vtrans)
  unsigned short* Att  = (unsigned short*)(ws + 61210624);            // 8,519,680
  unsigned short* Vtg  = (unsigned short*)(ws + 69730304);            // 16,908,288 -> total 86,638,592
  // split-K partials (identical layout to R11):
  //  region A (dead Xbf+Wq/k/v): PoA (2 splits) + PmlA
  //  region B (dead Vbuf): PoB (1 split) + PmlB
  unsigned short* PoA  = (unsigned short*)(ws);
  float2*         PmlA = (float2*)(ws + 17039360);
  unsigned short* PoB  = (unsigned short*)(ws + 44302336);
  float2*         PmlB = (float2*)(ws + 52822016);
  if (ws_size < 86638592) return;   // insufficient scratch -> visible first-call failure

  cvt_f32_bf16_v4<<<dim3(8192), dim3(256), 0, stream>>>(seq, Xbf, 2097152);
  cvt_w4<<<dim3(256, 4), dim3(256), 0, stream>>>(Wq, Wk, Wv, Wo, Wqb);
  proj_gemm<<<dim3(128, 4), dim3(256), 0, stream>>>(Xbf, Wkb, Kbuf, 12, 0, KLEN, 1.f);
  proj_gemm<<<dim3(128, 4), dim3(256), 0, stream>>>(Xbf, Wvb, Vbuf, 12, 0, KLEN, 1.f);
  proj_gemm<<<dim3(64, 4), dim3(256), 0, stream>>>(Xbf, Wqb, Qbuf, 11, 2048, QLEN, QSCALE);
  ns_proj<<<dim3(4, 32, 3), dim3(256), 0, stream>>>(nst, nsq, nsk, nsv, Qbuf, Kbuf, Vbuf);
  vtrans<<<dim3(65, 32), dim3(256), 0, stream>>>(Vbuf, Vtg);
  attn_kernel<<<dim3(51, 8, 4), dim3(256), 0, stream>>>(Qbuf, Kbuf, Vtg, PoA, PmlA, PoB, PmlB);
  attn_combine<<<dim3(65, 32), dim3(256), 0, stream>>>(PoA, PmlA, PoB, PmlB, Att);
  out_gemm<<<dim3(65, 4), dim3(256), 0, stream>>>(Att, Wob, out);
}

// Round 13
// 230.224 us; speedup vs baseline: 1.1156x; 1.1156x over previous
//
#include <hip/hip_runtime.h>

// ---------------- problem constants ----------------
#define NBATCH 4
#define SEQ    4096
#define DMODEL 512
#define NHEAD  8
#define HDIM   64
#define NSN    32
#define NXT    2048
#define QLEN   2080   // NXT + NSN
#define KLEN   4128   // SEQ + NSN

using bf16x8 = __attribute__((ext_vector_type(8))) short;
using f32x4  = __attribute__((ext_vector_type(4))) float;

typedef __attribute__((address_space(1))) unsigned int gu32;
typedef __attribute__((address_space(3))) unsigned int lu32;

// Q projection pre-scale: SCALE * log2(e) — softmax runs in exp2 domain
#define QSCALE 0.18033688f

__device__ __forceinline__ unsigned short f2bf(float f) {
  unsigned int u = __float_as_uint(f);
  u += 0x7FFF + ((u >> 16) & 1);          // RTNE
  return (unsigned short)(u >> 16);
}

__device__ __forceinline__ float bf2f(unsigned short u) {
  return __uint_as_float((unsigned int)u << 16);
}

__device__ __forceinline__ f32x4 mfma16(bf16x8 a, bf16x8 b, f32x4 c) {
  return __builtin_amdgcn_mfma_f32_16x16x32_bf16(a, b, c, 0, 0, 0);
}

__device__ __forceinline__ void gload_lds16(const void* g, void* lds_base) {
  __builtin_amdgcn_global_load_lds((const gu32*)g, (lu32*)lds_base, 16, 0, 0);
}

__device__ __forceinline__ unsigned int cvt_pk_bf16(float lo, float hi) {
  unsigned int r;
  asm("v_cvt_pk_bf16_f32 %0, %1, %2" : "=v"(r) : "v"(lo), "v"(hi));
  return r;
}

// ---------------- fp32 -> bf16 converts ----------------
__global__ __launch_bounds__(256) void cvt_f32_bf16_v4(const float* __restrict__ src,
                                                       unsigned short* __restrict__ dst, int n4) {
  int i = blockIdx.x * 256 + threadIdx.x;
  if (i >= n4) return;
  float4 v = reinterpret_cast<const float4*>(src)[i];
  ushort4 r;
  r.x = f2bf(v.x); r.y = f2bf(v.y); r.z = f2bf(v.z); r.w = f2bf(v.w);
  reinterpret_cast<ushort4*>(dst)[i] = r;
}

__global__ __launch_bounds__(256) void cvt_w4(const float* __restrict__ a, const float* __restrict__ b,
                                              const float* __restrict__ c, const float* __restrict__ d,
                                              unsigned short* __restrict__ dst) {
  const float* s = blockIdx.y == 0 ? a : blockIdx.y == 1 ? b : blockIdx.y == 2 ? c : d;
  int i = blockIdx.x * 256 + threadIdx.x;   // 65536 float4 per matrix
  float4 v = reinterpret_cast<const float4*>(s)[i];
  ushort4 r;
  r.x = f2bf(v.x); r.y = f2bf(v.y); r.z = f2bf(v.z); r.w = f2bf(v.w);
  reinterpret_cast<ushort4*>(dst)[(size_t)blockIdx.y * 65536 + i] = r;
}

// ---------------- seq projection GEMM (m97 structure, known-good) ----------------
__global__ __launch_bounds__(256) void proj_gemm(const unsigned short* __restrict__ X,
                                                 const unsigned short* __restrict__ W,
                                                 unsigned short* __restrict__ Out,
                                                 int rpb_shift, int row_off, int out_L, float scale) {
  __shared__ unsigned short As[128 * 32];
  __shared__ unsigned short Bs[128 * 32];
  const int tid = threadIdx.x;
  const int w = tid >> 6, l = tid & 63;
  const int lg = l >> 4, lr = l & 15;
  const int row0 = blockIdx.x * 128, col0 = blockIdx.y * 128;
  const int wr = (w >> 1) * 64, wc = (w & 1) * 64;
  const int mask = (1 << rpb_shift) - 1;

  f32x4 acc[4][4];
#pragma unroll
  for (int m = 0; m < 4; ++m)
#pragma unroll
    for (int n = 0; n < 4; ++n) acc[m][n] = (f32x4){0.f, 0.f, 0.f, 0.f};

  const int sr = w * 16 + (l >> 2);
  const int sc = (l & 3) * 8;

  for (int k0 = 0; k0 < 512; k0 += 32) {
#pragma unroll
    for (int i = 0; i < 2; ++i) {
      int gr = row0 + sr + i * 64;
      int xrow = ((gr >> rpb_shift) << 12) + row_off + (gr & mask);
      const unsigned short* gpa = X + (size_t)xrow * 512 + k0 + sc;
      gload_lds16(gpa, (char*)As + i * 4096 + w * 1024);
      const unsigned short* gpb = W + (size_t)(col0 + sr + i * 64) * 512 + k0 + sc;
      gload_lds16(gpb, (char*)Bs + i * 4096 + w * 1024);
    }
    __syncthreads();
    bf16x8 av[4], bv[4];
#pragma unroll
    for (int m = 0; m < 4; ++m) av[m] = *(const bf16x8*)&As[(wr + m * 16 + lr) * 32 + lg * 8];
#pragma unroll
    for (int n = 0; n < 4; ++n) bv[n] = *(const bf16x8*)&Bs[(wc + n * 16 + lr) * 32 + lg * 8];
#pragma unroll
    for (int m = 0; m < 4; ++m)
#pragma unroll
      for (int n = 0; n < 4; ++n) acc[m][n] = mfma16(av[m], bv[n], acc[m][n]);
    __syncthreads();
  }

#pragma unroll
  for (int m = 0; m < 4; ++m) {
    int crow = row0 + wr + m * 16 + lg * 4;
#pragma unroll
    for (int n = 0; n < 4; ++n) {
      int ccol = col0 + wc + n * 16 + lr;
      int hh = ccol >> 6, dd = ccol & 63;
#pragma unroll
      for (int r = 0; r < 4; ++r) {
        int cr = crow + r;
        int bb = cr >> rpb_shift, ii = cr & mask;
        Out[(((size_t)bb * NHEAD + hh) * out_L + ii) * HDIM + dd] = f2bf(acc[m][n][r] * scale);
      }
    }
  }
}

// ---------------- ns projections ----------------
__global__ __launch_bounds__(256) void ns_proj(const float* __restrict__ nst,
                                               const float* __restrict__ Wnq, const float* __restrict__ Wnk,
                                               const float* __restrict__ Wnv,
                                               unsigned short* __restrict__ Qb, unsigned short* __restrict__ Kb,
                                               unsigned short* __restrict__ Vb) {
  const int oc = blockIdx.x, n = blockIdx.y, p = blockIdx.z;
  const float* W = p == 0 ? Wnq : p == 1 ? Wnk : Wnv;
  unsigned short* Out = p == 0 ? Qb : p == 1 ? Kb : Vb;
  const int out_L = p == 0 ? QLEN : KLEN;
  const int orow = p == 0 ? NXT + n : SEQ + n;
  const float scale = p == 0 ? QSCALE : 1.f;

  __shared__ float xs[NBATCH][DMODEL];
  __shared__ float red[NBATCH][128];
  const int tid = threadIdx.x;
  for (int idx = tid; idx < NBATCH * DMODEL; idx += 256)
    xs[idx >> 9][idx & 511] = nst[(size_t)((idx >> 9) * NSN + n) * DMODEL + (idx & 511)];
  __syncthreads();

  const int o = oc * 128 + (tid & 127);
  const int dh = tid >> 7;
  float a0 = 0.f, a1 = 0.f, a2 = 0.f, a3 = 0.f;
  const float* wp = W + (size_t)n * DMODEL * DMODEL + o;
#pragma unroll 8
  for (int d = dh * 256; d < dh * 256 + 256; ++d) {
    float wv = wp[(size_t)d * DMODEL];
    a0 += xs[0][d] * wv; a1 += xs[1][d] * wv; a2 += xs[2][d] * wv; a3 += xs[3][d] * wv;
  }
  if (dh == 1) { red[0][tid & 127] = a0; red[1][tid & 127] = a1; red[2][tid & 127] = a2; red[3][tid & 127] = a3; }
  __syncthreads();
  if (dh == 0) {
    a0 += red[0][tid & 127]; a1 += red[1][tid & 127]; a2 += red[2][tid & 127]; a3 += red[3][tid & 127];
    int hh = o >> 6, dd = o & 63;
    float v[4] = {a0, a1, a2, a3};
#pragma unroll
    for (int b = 0; b < NBATCH; ++b)
      Out[(((size_t)b * NHEAD + hh) * out_L + orow) * HDIM + dd] = f2bf(v[b] * scale);
  }
}

// ---------------- global V transpose: Vt[bh][d][kv] = V[bh][kv][d] ----------------
__global__ __launch_bounds__(256) void vtrans(const unsigned short* __restrict__ V,
                                              unsigned short* __restrict__ Vt) {
  __shared__ unsigned short t[64 * 64];
  const int tid = threadIdx.x;
  const int kv0 = blockIdx.x * 64, bh = blockIdx.y;
  const unsigned short* Vhp = V + (size_t)bh * KLEN * HDIM;
  unsigned short* Vtp = Vt + (size_t)bh * HDIM * KLEN;

#pragma unroll
  for (int i = 0; i < 2; ++i) {
    int c = i * 256 + tid;
    int row = c >> 3, c8 = c & 7;
    int kvg = kv0 + row; if (kvg > KLEN - 1) kvg = KLEN - 1;
    int4 v4 = *(const int4*)(Vhp + (size_t)kvg * HDIM + c8 * 8);
    *(int4*)&t[row * 64 + ((c8 ^ ((row >> 3) & 7)) * 8)] = v4;
  }
  __syncthreads();
#pragma unroll
  for (int i = 0; i < 2; ++i) {
    int c = i * 256 + tid;
    int d = c >> 3, k8 = c & 7;
    if (kv0 + k8 * 8 <= KLEN - 8) {
      unsigned int wd[4];
#pragma unroll
      for (int jj = 0; jj < 4; ++jj) {
        int ka = k8 * 8 + jj * 2, kb2 = ka + 1;
        unsigned int lo = t[ka  * 64 + (((d >> 3) ^ ((ka  >> 3) & 7)) * 8) + (d & 7)];
        unsigned int hi = t[kb2 * 64 + (((d >> 3) ^ ((kb2 >> 3) & 7)) * 8) + (d & 7)];
        wd[jj] = lo | (hi << 16);
      }
      int4 o; o.x = wd[0]; o.y = wd[1]; o.z = wd[2]; o.w = wd[3];
      *(int4*)(Vtp + (size_t)d * KLEN + kv0 + k8 * 8) = o;
    }
  }
}

// ---------------- flash attention (R13: split-K x3 + double-buffered DMA) ----------
// R11 (passing, 138us) with R9's double-buffer restored: tile t+1's global_load_lds
// issued BEFORE computing tile t; the single per-tile barrier covers both the DMA
// drain and the readers. Removes the serialized ~500cy DMA wait that capped R11's
// occupancy at 34% (single-buffer stage->barrier->compute exposed latency per tile).
// LDS 32KB -> 5 blocks/CU (>= the ~3 achieved). All else identical to R11.
__global__ __launch_bounds__(256) void attn_kernel(const unsigned short* __restrict__ Qb,
                                                   const unsigned short* __restrict__ Kb,
                                                   const unsigned short* __restrict__ Vtg,
                                                   unsigned short* __restrict__ PoA,
                                                   float2* __restrict__ PmlA,
                                                   unsigned short* __restrict__ PoB,
                                                   float2* __restrict__ PmlB) {
  __shared__ unsigned short Ks[2][64 * 64];   // 8 KB x2 [kv][d] swizzled
  __shared__ unsigned short Vs[2][64 * 64];   // 8 KB x2 [d][kv] swizzled

  const int tid = threadIdx.x;
  const int w = tid >> 6, l = tid & 63;
  const int lg = l >> 4, lr = l & 15;
  const bool geven = (l & 16) == 0;
  const int bx = (int)blockIdx.x;
  const int qb = 32 - bx / 3;                          // big q-blocks first
  const int sp = bx - 3 * (32 - qb);
  const int bh = (int)blockIdx.z * NHEAD + (int)blockIdx.y;
  const int q0 = qb * 64;
  const int base = NXT + q0;
  const int nkb = (base >> 6) + 1;                     // total tiles for this q-block
  const int t0 = (sp * nkb) / 3;
  const int t1 = ((sp + 1) * nkb) / 3;

  const unsigned short* Qh = Qb + (size_t)bh * QLEN * HDIM;
  const unsigned short* Kh = Kb + (size_t)bh * KLEN * HDIM;
  const unsigned short* Vh = Vtg + (size_t)bh * HDIM * KLEN;   // [64][KLEN]

  int qrow = q0 + w * 16 + lr; if (qrow > QLEN - 1) qrow = QLEN - 1;
  const bf16x8 qa0 = *(const bf16x8*)(Qh + (size_t)qrow * HDIM + lg * 8);
  const bf16x8 qa1 = *(const bf16x8*)(Qh + (size_t)qrow * HDIM + 32 + lg * 8);

  f32x4 acc[4];
#pragma unroll
  for (int n = 0; n < 4; ++n) acc[n] = (f32x4){0.f, 0.f, 0.f, 0.f};
  float m_r = 0.f, lsum = 0.f;                         // per-lane scalars (q = l&15)

  const bf16x8 ones = {(short)0x3F80, (short)0x3F80, (short)0x3F80, (short)0x3F80,
                       (short)0x3F80, (short)0x3F80, (short)0x3F80, (short)0x3F80};

  // staging lane geometry (involutive chunk swizzle, rule #21)
  const int rloc = l >> 3;
  const int jsrc = ((l & 7) ^ rloc) * 8;

#define STAGE(buf, kv0s)                                                            \
  {                                                                                 \
    if ((kv0s) + 64 <= KLEN) {                                                      \
      _Pragma("unroll")                                                             \
      for (int i = 0; i < 2; ++i) {                                                 \
        const int r8 = (w * 2 + i) * 8;                                             \
        gload_lds16(Kh + (size_t)((kv0s) + r8 + rloc) * HDIM + jsrc,                \
                    &Ks[buf][r8 * 64]);                                             \
        gload_lds16(Vh + (size_t)(r8 + rloc) * KLEN + (kv0s) + jsrc,                \
                    &Vs[buf][r8 * 64]);                                             \
      }                                                                             \
    } else {                                                                        \
      _Pragma("unroll")                                                             \
      for (int i = 0; i < 2; ++i) {                                                 \
        const int r8 = (w * 2 + i) * 8;                                             \
        int kr = (kv0s) + r8 + rloc; if (kr > KLEN - 1) kr = KLEN - 1;              \
        gload_lds16(Kh + (size_t)kr * HDIM + jsrc, &Ks[buf][r8 * 64]);              \
        int vc = (kv0s) + jsrc; if (vc > KLEN - 8) vc = KLEN - 8;                   \
        gload_lds16(Vh + (size_t)(r8 + rloc) * KLEN + vc, &Vs[buf][r8 * 64]);       \
      }                                                                             \
    }                                                                               \
  }

  STAGE(0, t0 * 64)
  __syncthreads();
  int cur = 0;

  for (int kb = t0; kb < t1; ++kb) {
    if (kb + 1 < t1) STAGE(cur ^ 1, (kb + 1) * 64)     // DMA lands during compute

    const unsigned short* Kc = &Ks[cur][0];
    const unsigned short* Vc = &Vs[cur][0];
    const int kv0 = kb * 64;

    // S^T = K Q^T - m : lane owns q=l&15; s[n][r] is kv = kv0 + n*16 + lg*4 + r
    const f32x4 minit = {-m_r, -m_r, -m_r, -m_r};
    f32x4 s[4];
#pragma unroll
    for (int n = 0; n < 4; ++n) {
      const int rk = n * 16 + lr;
      const bf16x8 k0 = *(const bf16x8*)&Kc[rk * 64 + ((lg ^ (rk & 7)) * 8)];
      const bf16x8 k1 = *(const bf16x8*)&Kc[rk * 64 + (((4 + lg) ^ (rk & 7)) * 8)];
      s[n] = mfma16(k0, qa0, minit);                   // swapped operands
      s[n] = mfma16(k1, qa1, s[n]);
    }

    if (kb == nkb - 1) {                               // causal mask (diag tile, sp==2)
      const int qk_lim = base + w * 16 + lr;
#pragma unroll
      for (int n = 0; n < 4; ++n)
#pragma unroll
        for (int r = 0; r < 4; ++r)
          if (kv0 + n * 16 + lg * 4 + r > qk_lim) s[n][r] = -1e30f;
    }

    // local max via v_max3-friendly triples; __any makes the check wave-global
    float a3 = fmaxf(fmaxf(s[0][0], s[0][1]), s[0][2]);
    float b3 = fmaxf(fmaxf(s[0][3], s[1][0]), s[1][1]);
    float c3 = fmaxf(fmaxf(s[1][2], s[1][3]), s[2][0]);
    float d3 = fmaxf(fmaxf(s[2][1], s[2][2]), s[2][3]);
    float e3 = fmaxf(fmaxf(s[3][0], s[3][1]), s[3][2]);
    float rl = fmaxf(fmaxf(a3, b3), c3);
    rl = fmaxf(fmaxf(rl, d3), e3);
    rl = fmaxf(rl, s[3][3]);

    if (__any(rl > 11.5f)) {                           // T13 defer-max (rare branch)
      float rmax = fmaxf(rl, __shfl_xor(rl, 16));      // full cross-q-lane max
      rmax = fmaxf(rmax, __shfl_xor(rmax, 32));
      float dl = fmaxf(rmax, 0.f);
      float sc = exp2f(-dl);
      lsum *= sc; m_r += dl;
#pragma unroll
      for (int n = 0; n < 4; ++n) {
        acc[n][0] *= sc; acc[n][1] *= sc; acc[n][2] *= sc; acc[n][3] *= sc;
#pragma unroll
        for (int r = 0; r < 4; ++r) s[n][r] = exp2f(s[n][r] - dl);
      }
    } else {
#pragma unroll
      for (int n = 0; n < 4; ++n)
#pragma unroll
        for (int r = 0; r < 4; ++r) s[n][r] = exp2f(s[n][r]);
    }

    // ---- P redistribution to PV B-operand frags (registers only) ----
    unsigned int wpk[4][2];
#pragma unroll
    for (int n = 0; n < 4; ++n) {
      wpk[n][0] = cvt_pk_bf16(s[n][0], s[n][1]);
      wpk[n][1] = cvt_pk_bf16(s[n][2], s[n][3]);
    }
    bf16x8 pb[2];
#pragma unroll
    for (int ks = 0; ks < 2; ++ks) {
      unsigned int A0 = wpk[2 * ks][0], B0 = wpk[2 * ks + 1][0];
      unsigned int A1 = wpk[2 * ks][1], B1 = wpk[2 * ks + 1][1];
      asm("v_permlane32_swap_b32 %0, %1" : "+v"(A0), "+v"(B0));
      asm("v_permlane32_swap_b32 %0, %1" : "+v"(A1), "+v"(B1));
      unsigned int sA0 = __builtin_amdgcn_ds_swizzle(A0, 0x401F);  // lane ^16
      unsigned int sA1 = __builtin_amdgcn_ds_swizzle(A1, 0x401F);
      unsigned int sB0 = __builtin_amdgcn_ds_swizzle(B0, 0x401F);
      unsigned int sB1 = __builtin_amdgcn_ds_swizzle(B1, 0x401F);
      int4 words;
      words.x = geven ? A0 : sB0;
      words.y = geven ? A1 : sB1;
      words.z = geven ? sA0 : B0;
      words.w = geven ? sA1 : B1;
      pb[ks] = *(bf16x8*)&words;    // B-frag: P[kv=32ks+(l>>4)*8+j][q=l&15]
    }

    // lsum via ones-MFMA (A=ones)
    f32x4 acc_s = (f32x4){0.f, 0.f, 0.f, 0.f};
    acc_s = mfma16(ones, pb[0], acc_s);
    acc_s = mfma16(ones, pb[1], acc_s);
    lsum += acc_s[0];

    // PV: out^T[d][q] += V^T[d][kv] P[kv][q]
#pragma unroll
    for (int n = 0; n < 4; ++n) {
      const int rv = n * 16 + lr;
#pragma unroll
      for (int ks = 0; ks < 2; ++ks) {
        const bf16x8 vv = *(const bf16x8*)&Vc[rv * 64 + (((ks * 4 + lg) ^ (rv & 7)) * 8)];
        acc[n] = mfma16(vv, pb[ks], acc[n]);
      }
    }

    __syncthreads();   // readers of buf[cur] done; next tile's DMA drained
    cur ^= 1;
  }

  // store partials (packed 8B): acc[n][r] -> [q][d = n*16+lg*4+r], unnormalized
  const int qi = q0 + w * 16 + lr;
  if (qi < QLEN) {
    unsigned short* po; float2* pml; size_t rowp;
    if (sp < 2) { rowp = (size_t)(sp * 32 + bh) * QLEN + qi; po = PoA + rowp * 64; pml = PmlA + rowp; }
    else        { rowp = (size_t)bh * QLEN + qi;             po = PoB + rowp * 64; pml = PmlB + rowp; }
#pragma unroll
    for (int n = 0; n < 4; ++n) {
      ushort4 pk;
      pk.x = f2bf(acc[n][0]); pk.y = f2bf(acc[n][1]);
      pk.z = f2bf(acc[n][2]); pk.w = f2bf(acc[n][3]);
      *(ushort4*)(po + n * 16 + lg * 4) = pk;
    }
    if (l < 16) *pml = (float2){m_r, lsum};
  }
#undef STAGE
}

// ---------------- split-K combine (3-way) ----------------
__global__ __launch_bounds__(256) void attn_combine(const unsigned short* __restrict__ PoA,
                                                    const float2* __restrict__ PmlA,
                                                    const unsigned short* __restrict__ PoB,
                                                    const float2* __restrict__ PmlB,
                                                    unsigned short* __restrict__ Att) {
  const int bh = blockIdx.y;
  const int idx = blockIdx.x * 256 + threadIdx.x;
  const int qi = idx >> 3, dc = (idx & 7) * 8;
  const size_t row = (size_t)bh * QLEN + qi;
  const float2 ml0 = PmlA[row];
  const float2 ml1 = PmlA[(size_t)32 * QLEN + row];
  const float2 ml2 = PmlB[row];
  const float mm = fmaxf(fmaxf(ml0.x, ml1.x), ml2.x);
  float s0 = exp2f(ml0.x - mm), s1 = exp2f(ml1.x - mm), s2 = exp2f(ml2.x - mm);
  const float inv = 1.f / (ml0.y * s0 + ml1.y * s1 + ml2.y * s2);
  s0 *= inv; s1 *= inv; s2 *= inv;
  const bf16x8 o0 = *(const bf16x8*)(PoA + row * 64 + dc);
  const bf16x8 o1 = *(const bf16x8*)(PoA + ((size_t)32 * QLEN + row) * 64 + dc);
  const bf16x8 o2 = *(const bf16x8*)(PoB + row * 64 + dc);
  unsigned short out[8];
#pragma unroll
  for (int j = 0; j < 8; ++j)
    out[j] = f2bf(bf2f((unsigned short)o0[j]) * s0 + bf2f((unsigned short)o1[j]) * s1 +
                  bf2f((unsigned short)o2[j]) * s2);
  const int b = bh >> 3, h = bh & 7;
  *(int4*)(Att + ((size_t)b * QLEN + qi) * DMODEL + h * HDIM + dc) = *(int4*)out;
}

// ---------------- output GEMM (unchanged) ----------------
__global__ __launch_bounds__(256) void out_gemm(const unsigned short* __restrict__ A,
                                                const unsigned short* __restrict__ W,
                                                float* __restrict__ Out) {
  __shared__ unsigned short As[128 * 32];
  __shared__ unsigned short Bs[128 * 32];
  const int tid = threadIdx.x;
  const int w = tid >> 6, l = tid & 63;
  const int lg = l >> 4, lr = l & 15;
  const int row0 = blockIdx.x * 128, col0 = blockIdx.y * 128;
  const int wr = (w >> 1) * 64, wc = (w & 1) * 64;

  f32x4 acc[4][4];
#pragma unroll
  for (int m = 0; m < 4; ++m)
#pragma unroll
    for (int n = 0; n < 4; ++n) acc[m][n] = (f32x4){0.f, 0.f, 0.f, 0.f};

  const int sr = w * 16 + (l >> 2);
  const int sc = (l & 3) * 8;

  for (int k0 = 0; k0 < 512; k0 += 32) {
#pragma unroll
    for (int i = 0; i < 2; ++i) {
      const unsigned short* gpa = A + (size_t)(row0 + sr + i * 64) * 512 + k0 + sc;
      gload_lds16(gpa, (char*)As + i * 4096 + w * 1024);
      const unsigned short* gpb = W + (size_t)(col0 + sr + i * 64) * 512 + k0 + sc;
      gload_lds16(gpb, (char*)Bs + i * 4096 + w * 1024);
    }
    __syncthreads();
    bf16x8 av[4], bv[4];
#pragma unroll
    for (int m = 0; m < 4; ++m) av[m] = *(const bf16x8*)&As[(wr + m * 16 + lr) * 32 + lg * 8];
#pragma unroll
    for (int n = 0; n < 4; ++n) bv[n] = *(const bf16x8*)&Bs[(wc + n * 16 + lr) * 32 + lg * 8];
#pragma unroll
    for (int m = 0; m < 4; ++m)
#pragma unroll
      for (int n = 0; n < 4; ++n) acc[m][n] = mfma16(av[m], bv[n], acc[m][n]);
    __syncthreads();
  }

#pragma unroll
  for (int m = 0; m < 4; ++m) {
    int crow = row0 + wr + m * 16 + lg * 4;
#pragma unroll
    for (int n = 0; n < 4; ++n) {
      int ccol = col0 + wc + n * 16 + lr;
#pragma unroll
      for (int r = 0; r < 4; ++r) {
        int cr = crow + r;
        int bb = cr / QLEN, ii = cr - bb * QLEN;
        size_t off = ii < NXT
                       ? ((size_t)bb * NXT + ii) * DMODEL + ccol
                       : (size_t)NBATCH * NXT * DMODEL + ((size_t)bb * NSN + (ii - NXT)) * DMODEL + ccol;
        Out[off] = acc[m][n][r];
      }
    }
  }
}

// ---------------- host launch ----------------
extern "C" void kernel_launch(void* const* d_in, const int* in_sizes, int n_in,
                              void* d_out, int out_size, void* d_ws, size_t ws_size,
                              hipStream_t stream) {
  const float* seq = (const float*)d_in[0];
  const float* nst = (const float*)d_in[2];
  const float* Wq  = (const float*)d_in[5];
  const float* Wk  = (const float*)d_in[6];
  const float* Wv  = (const float*)d_in[7];
  const float* nsq = (const float*)d_in[8];
  const float* nsk = (const float*)d_in[9];
  const float* nsv = (const float*)d_in[10];
  const float* Wo  = (const float*)d_in[11];
  float* out = (float*)d_out;

  char* ws = (char*)d_ws;
  unsigned short* Xbf  = (unsigned short*)(ws);                       // 16,777,216 (dead after Q proj)
  unsigned short* Wqb  = (unsigned short*)(ws + 16777216);            // 524,288 x4 (Wq/k/v dead after projs)
  unsigned short* Wkb  = Wqb + 262144;
  unsigned short* Wvb  = Wkb + 262144;
  unsigned short* Wob  = Wvb + 262144;                                // LIVE until out_gemm
  unsigned short* Qbuf = (unsigned short*)(ws + 18874368);            // 8,519,680
  unsigned short* Kbuf = (unsigned short*)(ws + 27394048);            // 16,908,288
  unsigned short* Vbuf = (unsigned short*)(ws + 44302336);            // 16,908,288 (dead after vtrans)
  unsigned short* Att  = (unsigned short*)(ws + 61210624);            // 8,519,680
  unsigned short* Vtg  = (unsigned short*)(ws + 69730304);            // 16,908,288 -> total 86,638,592
  // split-K partials (identical layout to R11):
  //  region A (dead Xbf+Wq/k/v, [0, 18,349,568)): PoA 17,039,360 + PmlA 1,064,960 ✓
  //  region B (dead Vbuf, [44,302,336, 61,210,624)): PoB 8,519,680 + PmlB 532,480 ✓
  unsigned short* PoA  = (unsigned short*)(ws);
  float2*         PmlA = (float2*)(ws + 17039360);
  unsigned short* PoB  = (unsigned short*)(ws + 44302336);
  float2*         PmlB = (float2*)(ws + 52822016);
  if (ws_size < 86638592) return;   // insufficient scratch -> visible first-call failure

  cvt_f32_bf16_v4<<<dim3(8192), dim3(256), 0, stream>>>(seq, Xbf, 2097152);
  cvt_w4<<<dim3(256, 4), dim3(256), 0, stream>>>(Wq, Wk, Wv, Wo, Wqb);
  proj_gemm<<<dim3(128, 4), dim3(256), 0, stream>>>(Xbf, Wkb, Kbuf, 12, 0, KLEN, 1.f);
  proj_gemm<<<dim3(128, 4), dim3(256), 0, stream>>>(Xbf, Wvb, Vbuf, 12, 0, KLEN, 1.f);
  proj_gemm<<<dim3(64, 4), dim3(256), 0, stream>>>(Xbf, Wqb, Qbuf, 11, 2048, QLEN, QSCALE);
  ns_proj<<<dim3(4, 32, 3), dim3(256), 0, stream>>>(nst, nsq, nsk, nsv, Qbuf, Kbuf, Vbuf);
  vtrans<<<dim3(65, 32), dim3(256), 0, stream>>>(Vbuf, Vtg);
  attn_kernel<<<dim3(99, 8, 4), dim3(256), 0, stream>>>(Qbuf, Kbuf, Vtg, PoA, PmlA, PoB, PmlB);
  attn_combine<<<dim3(65, 32), dim3(256), 0, stream>>>(PoA, PmlA, PoB, PmlB, Att);
  out_gemm<<<dim3(65, 4), dim3(256), 0, stream>>>(Att, Wob, out);
}